// Round 1
// baseline (283.319 us; speedup 1.0000x reference)
//
#include <hip/hip_runtime.h>
#include <hip/hip_fp16.h>
#include <math.h>

typedef _Float16 half_t;
typedef __attribute__((ext_vector_type(8))) _Float16 f16x8;
typedef __attribute__((ext_vector_type(4))) float f32x4;

#define BPTT 32
#define BSZ 32
#define NTOK 2000
#define NTOKP 2048
#define NINP 1024
#define NHID 256
#define TB 1024  /* BPTT*BSZ */
#define NH2 65536

// ---------------- conversion kernels ----------------

// f32 -> (hi fp16, lo fp16) with zero-padding of columns [cols, 2048)
__global__ void cvt_split_pad_k(const float* __restrict__ in, half_t* __restrict__ hi,
                                half_t* __restrict__ lo, int cols) {
  int idx = blockIdx.x * 256 + threadIdx.x;  // rows*2048 total
  int r = idx >> 11, c = idx & 2047;
  float v = (c < cols) ? in[(size_t)r * cols + c] : 0.f;
  half_t h = (half_t)v;
  hi[idx] = h;
  lo[idx] = (half_t)(v - (float)h);
}

__global__ void cvt_half_k(const float* __restrict__ in, half_t* __restrict__ out, int n) {
  int idx = blockIdx.x * 256 + threadIdx.x;
  if (idx < n) out[idx] = (half_t)in[idx];
}

// dec_w [2000][256] -> fp16 [2048][256] with zero rows [2000,2048)
__global__ void cvt_pad_rows_k(const float* __restrict__ in, half_t* __restrict__ out,
                               int rows_valid) {
  int idx = blockIdx.x * 256 + threadIdx.x;  // 2048*256
  int r = idx >> 8, c = idx & 255;
  float v = (r < rows_valid) ? in[(size_t)r * 256 + c] : 0.f;
  out[idx] = (half_t)v;
}

// WWT[h*256+r][c] = wfef_w[r*256+c][h]  (fp16 output)
__global__ void permute_wfef_k(const float* __restrict__ wfef, half_t* __restrict__ wwt) {
  __shared__ float tile[32][33];
  int r = blockIdx.x, cb = blockIdx.y, hb = blockIdx.z;
  int tx = threadIdx.x, ty = threadIdx.y;
#pragma unroll
  for (int ii = 0; ii < 4; ii++) {
    int cl = ty + ii * 8;
    tile[cl][tx] = wfef[((size_t)(r * 256 + cb * 32 + cl)) * 256 + hb * 32 + tx];
  }
  __syncthreads();
#pragma unroll
  for (int ii = 0; ii < 4; ii++) {
    int hl = ty + ii * 8;
    wwt[((size_t)(hb * 32 + hl) * 256 + r) * 256 + cb * 32 + tx] = (half_t)tile[tx][hl];
  }
}

// ---------------- plain fp16 GEMM, 128x128 tile, C = A @ B^T ----------------
// A: [M][K] fp16 row-major, B: [N][K] fp16 row-major (i.e. B^T input), K%32==0.
// EP: 0 = store half (no bias)   [M-precompute]
//     1 = store half (acc+bias)  [obs]
//     2 = store f32 (no bias)    [V]
//     3 = store f32 (acc+bias) with col guard gc<nvalid, ldc=nvalid [decoder]
template <int EP>
__global__ __launch_bounds__(256) void gemm128_k(const half_t* __restrict__ A,
                                                 const half_t* __restrict__ B,
                                                 void* __restrict__ C,
                                                 const float* __restrict__ bias, int K,
                                                 int ldc, int nvalid) {
  __shared__ half_t As[128 * 32];
  __shared__ half_t Bs[128 * 32];
  const int tid = threadIdx.x;
  const int lane = tid & 63, wave = tid >> 6;
  const int wr = wave >> 1, wc = wave & 1;
  const int row0 = blockIdx.x * 128, col0 = blockIdx.y * 128;
  const int srow = tid >> 2, sseg = tid & 3;
  const size_t aoff = (size_t)(row0 + srow) * K + sseg * 8;
  const size_t boff = (size_t)(col0 + srow) * K + sseg * 8;
  const int fr = lane & 15, fq = lane >> 4;

  f32x4 acc[4][4];
#pragma unroll
  for (int m = 0; m < 4; m++)
#pragma unroll
    for (int n = 0; n < 4; n++) acc[m][n] = (f32x4)(0.0f);

  for (int k0 = 0; k0 < K; k0 += 32) {
    f16x8 a0 = *(const f16x8*)(A + aoff + k0);
    f16x8 a1 = *(const f16x8*)(A + aoff + (size_t)64 * K + k0);
    f16x8 b0 = *(const f16x8*)(B + boff + k0);
    f16x8 b1 = *(const f16x8*)(B + boff + (size_t)64 * K + k0);
    __syncthreads();
    *(f16x8*)(As + srow * 32 + sseg * 8) = a0;
    *(f16x8*)(As + (srow + 64) * 32 + sseg * 8) = a1;
    *(f16x8*)(Bs + srow * 32 + sseg * 8) = b0;
    *(f16x8*)(Bs + (srow + 64) * 32 + sseg * 8) = b1;
    __syncthreads();
    f16x8 af[4], bf[4];
#pragma unroll
    for (int m = 0; m < 4; m++)
      af[m] = *(const f16x8*)(As + (wr * 64 + m * 16 + fr) * 32 + fq * 8);
#pragma unroll
    for (int n = 0; n < 4; n++)
      bf[n] = *(const f16x8*)(Bs + (wc * 64 + n * 16 + fr) * 32 + fq * 8);
#pragma unroll
    for (int m = 0; m < 4; m++)
#pragma unroll
      for (int n = 0; n < 4; n++)
        acc[m][n] = __builtin_amdgcn_mfma_f32_16x16x32_f16(af[m], bf[n], acc[m][n], 0, 0, 0);
  }

#pragma unroll
  for (int m = 0; m < 4; m++) {
#pragma unroll
    for (int n = 0; n < 4; n++) {
#pragma unroll
      for (int j = 0; j < 4; j++) {
        int gr = row0 + wr * 64 + m * 16 + fq * 4 + j;
        int gc = col0 + wc * 64 + n * 16 + fr;
        float v = acc[m][n][j];
        if (EP == 0) {
          ((half_t*)C)[(size_t)gr * ldc + gc] = (half_t)v;
        } else if (EP == 1) {
          ((half_t*)C)[(size_t)gr * ldc + gc] = (half_t)(v + bias[gc]);
        } else if (EP == 2) {
          ((float*)C)[(size_t)gr * ldc + gc] = v;
        } else {
          if (gc < nvalid) ((float*)C)[(size_t)gr * ldc + gc] = v + bias[gc];
        }
      }
    }
  }
}

// ---------------- split-precision RBF GEMM (3-term hi/lo), 128x64 tile ----------------
// C[gr][gc] = cos( sum_k A[gr][k]*B[gc][k] + bias[gc] ) * RBF_SCALE, fp16 store.
__global__ __launch_bounds__(256) void gemm1_split3_k(
    const half_t* __restrict__ Ahi, const half_t* __restrict__ Alo,
    const half_t* __restrict__ Bhi, const half_t* __restrict__ Blo,
    const float* __restrict__ bias, half_t* __restrict__ C, int K, int ldc) {
  __shared__ half_t Ash[128 * 32];
  __shared__ half_t Asl[128 * 32];
  __shared__ half_t Bsh[64 * 32];
  __shared__ half_t Bsl[64 * 32];
  const int tid = threadIdx.x;
  const int lane = tid & 63, wave = tid >> 6;
  const int wr = wave >> 1, wc = wave & 1;  // waves 2x2; wave tile 64x32
  const int row0 = blockIdx.x * 128, col0 = blockIdx.y * 64;
  const int srow = tid >> 2, sseg = tid & 3;
  const size_t aoff = (size_t)(row0 + srow) * K + sseg * 8;
  const size_t boff = (size_t)(col0 + srow) * K + sseg * 8;
  const int fr = lane & 15, fq = lane >> 4;

  f32x4 acc[4][2];
#pragma unroll
  for (int m = 0; m < 4; m++)
#pragma unroll
    for (int n = 0; n < 2; n++) acc[m][n] = (f32x4)(0.0f);

  for (int k0 = 0; k0 < K; k0 += 32) {
    f16x8 ah0 = *(const f16x8*)(Ahi + aoff + k0);
    f16x8 ah1 = *(const f16x8*)(Ahi + aoff + (size_t)64 * K + k0);
    f16x8 al0 = *(const f16x8*)(Alo + aoff + k0);
    f16x8 al1 = *(const f16x8*)(Alo + aoff + (size_t)64 * K + k0);
    f16x8 bh0 = *(const f16x8*)(Bhi + boff + k0);
    f16x8 bl0 = *(const f16x8*)(Blo + boff + k0);
    __syncthreads();
    *(f16x8*)(Ash + srow * 32 + sseg * 8) = ah0;
    *(f16x8*)(Ash + (srow + 64) * 32 + sseg * 8) = ah1;
    *(f16x8*)(Asl + srow * 32 + sseg * 8) = al0;
    *(f16x8*)(Asl + (srow + 64) * 32 + sseg * 8) = al1;
    *(f16x8*)(Bsh + srow * 32 + sseg * 8) = bh0;
    *(f16x8*)(Bsl + srow * 32 + sseg * 8) = bl0;
    __syncthreads();
    f16x8 afh[4], afl[4], bfh[2], bfl[2];
#pragma unroll
    for (int m = 0; m < 4; m++) {
      afh[m] = *(const f16x8*)(Ash + (wr * 64 + m * 16 + fr) * 32 + fq * 8);
      afl[m] = *(const f16x8*)(Asl + (wr * 64 + m * 16 + fr) * 32 + fq * 8);
    }
#pragma unroll
    for (int n = 0; n < 2; n++) {
      bfh[n] = *(const f16x8*)(Bsh + (wc * 32 + n * 16 + fr) * 32 + fq * 8);
      bfl[n] = *(const f16x8*)(Bsl + (wc * 32 + n * 16 + fr) * 32 + fq * 8);
    }
#pragma unroll
    for (int m = 0; m < 4; m++)
#pragma unroll
      for (int n = 0; n < 2; n++) {
        acc[m][n] = __builtin_amdgcn_mfma_f32_16x16x32_f16(afh[m], bfh[n], acc[m][n], 0, 0, 0);
        acc[m][n] = __builtin_amdgcn_mfma_f32_16x16x32_f16(afl[m], bfh[n], acc[m][n], 0, 0, 0);
        acc[m][n] = __builtin_amdgcn_mfma_f32_16x16x32_f16(afh[m], bfl[n], acc[m][n], 0, 0, 0);
      }
  }

  const float RBF_SCALE = 0.04419417382415922f;  // sqrt(2)/sqrt(1024)
#pragma unroll
  for (int m = 0; m < 4; m++) {
#pragma unroll
    for (int n = 0; n < 2; n++) {
#pragma unroll
      for (int j = 0; j < 4; j++) {
        int gr = row0 + wr * 64 + m * 16 + fq * 4 + j;
        int gc = col0 + wc * 32 + n * 16 + fr;
        float v = acc[m][n][j] + bias[gc];
        C[(size_t)gr * ldc + gc] = (half_t)(cosf(v) * RBF_SCALE);
      }
    }
  }
}

// ---------------- sequential scan: 32 blocks (one per batch sample) ----------------
// bn_pre[r] = sum_h bvec[h] * M[tb][h*256+r] + V[tb][r]; bn = bn_pre/||bn_pre||
__global__ __launch_bounds__(1024) void scan_k(const half_t* __restrict__ Mmat,
                                               const float* __restrict__ V,
                                               const float* __restrict__ b0,
                                               half_t* __restrict__ BN,
                                               float* __restrict__ bfinal) {
  __shared__ float bvec[256];
  __shared__ float partial[32][256];
  __shared__ float red[4];
  const int b = blockIdx.x, tid = threadIdx.x;
  const int hh = tid >> 5, rv = tid & 31;  // h-group (8 h each), r-group (8 r each)
  if (tid < 256) bvec[tid] = b0[b * 256 + tid];

  f16x8 cur[8];
  {
    const half_t* s0 = Mmat + (size_t)b * NH2;
#pragma unroll
    for (int k = 0; k < 8; k++)
      cur[k] = *(const f16x8*)(s0 + (hh * 8 + k) * 256 + rv * 8);
  }
  __syncthreads();

  for (int t = 0; t < 32; t++) {
    const int tn = (t < 31) ? (t + 1) : 31;
    const half_t* sn = Mmat + ((size_t)tn * 32 + b) * NH2;
    f16x8 nxt[8];
#pragma unroll
    for (int k = 0; k < 8; k++)
      nxt[k] = *(const f16x8*)(sn + (hh * 8 + k) * 256 + rv * 8);

    float acc[8];
#pragma unroll
    for (int j = 0; j < 8; j++) acc[j] = 0.f;
#pragma unroll
    for (int k = 0; k < 8; k++) {
      float bv = bvec[hh * 8 + k];
#pragma unroll
      for (int j = 0; j < 8; j++) acc[j] += bv * (float)cur[k][j];
    }
#pragma unroll
    for (int j = 0; j < 8; j++) partial[hh][rv * 8 + j] = acc[j];
    __syncthreads();  // partial ready

    float s = 0.f;
    if (tid < 256) {
#pragma unroll
      for (int g = 0; g < 32; g++) s += partial[g][tid];
      s += V[((size_t)t * 32 + b) * 256 + tid];
      float sq = s * s;
#pragma unroll
      for (int o = 32; o > 0; o >>= 1) sq += __shfl_xor(sq, o);
      if ((tid & 63) == 0) red[tid >> 6] = sq;
    }
    __syncthreads();  // red ready
    if (tid < 256) {
      float sumsq = red[0] + red[1] + red[2] + red[3];
      float bnv = s / sqrtf(sumsq);
      bvec[tid] = bnv;
      BN[((size_t)t * 32 + b) * 256 + tid] = (half_t)bnv;
      if (t == 31) bfinal[b * 256 + tid] = bnv;
    }
    __syncthreads();  // bvec ready for next step
#pragma unroll
    for (int k = 0; k < 8; k++) cur[k] = nxt[k];
  }
}

// ---------------- launch ----------------

extern "C" void kernel_launch(void* const* d_in, const int* in_sizes, int n_in,
                              void* d_out, int out_size, void* d_ws, size_t ws_size,
                              hipStream_t stream) {
  const float* input = (const float*)d_in[0];
  const float* b0 = (const float*)d_in[1];
  const float* RBF_w = (const float*)d_in[2];
  const float* RBF_b = (const float*)d_in[3];
  const float* emb_w = (const float*)d_in[4];
  const float* emb_b = (const float*)d_in[5];
  const float* wfef_w = (const float*)d_in[6];
  const float* wfef_b = (const float*)d_in[7];
  const float* dec_w = (const float*)d_in[8];
  const float* dec_b = (const float*)d_in[9];

  char* ws = (char*)d_ws;
  size_t off = 0;
  auto alloc = [&](size_t bytes) {
    void* p = ws + off;
    off += (bytes + 255) & ~(size_t)255;
    return p;
  };
  half_t* A1hi = (half_t*)alloc((size_t)TB * NTOKP * 2);
  half_t* A1lo = (half_t*)alloc((size_t)TB * NTOKP * 2);
  half_t* B1hi = (half_t*)alloc((size_t)NINP * NTOKP * 2);
  half_t* B1lo = (half_t*)alloc((size_t)NINP * NTOKP * 2);
  half_t* encA = (half_t*)alloc((size_t)TB * NINP * 2);
  half_t* B2 = (half_t*)alloc((size_t)NHID * NINP * 2);
  half_t* obsA = (half_t*)alloc((size_t)TB * NHID * 2);
  half_t* WBh = (half_t*)alloc((size_t)NHID * NHID * 2);
  half_t* B4 = (half_t*)alloc((size_t)2048 * NHID * 2);
  float* Vbuf = (float*)alloc((size_t)TB * NHID * 4);
  half_t* BN = (half_t*)alloc((size_t)TB * NHID * 2);
  half_t* WWT = (half_t*)alloc((size_t)NH2 * NHID * 2);
  half_t* Mmat = (half_t*)alloc((size_t)TB * NH2 * 2);
  if (off > ws_size) return;  // workspace too small: fail loudly (output stays zero)

  float* outp = (float*)d_out;
  float* bfinal = outp + (size_t)TB * NTOK;

  // conversions
  cvt_split_pad_k<<<(TB * NTOKP) / 256, 256, 0, stream>>>(input, A1hi, A1lo, NTOK);
  cvt_split_pad_k<<<(NINP * NTOKP) / 256, 256, 0, stream>>>(RBF_w, B1hi, B1lo, NTOK);
  cvt_half_k<<<(NHID * NINP) / 256, 256, 0, stream>>>(emb_w, B2, NHID * NINP);
  cvt_half_k<<<(NHID * NHID) / 256, 256, 0, stream>>>(wfef_b, WBh, NHID * NHID);
  cvt_pad_rows_k<<<(2048 * NHID) / 256, 256, 0, stream>>>(dec_w, B4, NTOK);
  permute_wfef_k<<<dim3(256, 8, 8), dim3(32, 8), 0, stream>>>(wfef_w, WWT);

  // encoded = cos(input @ RBF_w.T + RBF_b) * scale   [split precision]
  gemm1_split3_k<<<dim3(8, 16), 256, 0, stream>>>(A1hi, A1lo, B1hi, B1lo, RBF_b, encA,
                                                  NTOKP, NINP);
  // obs = encoded @ emb_w.T + emb_b
  gemm128_k<1><<<dim3(8, 2), 256, 0, stream>>>(encA, B2, obsA, emb_b, NINP, NHID, 0);
  // V = obs @ reshape(wfef_b)^T
  gemm128_k<2><<<dim3(8, 2), 256, 0, stream>>>(obsA, WBh, Vbuf, nullptr, NHID, NHID, 0);
  // M[tb][h*256+r] = sum_c obs[tb][c] * wfef_w[r*256+c][h]
  gemm128_k<0><<<dim3(8, 512), 256, 0, stream>>>(obsA, WWT, Mmat, nullptr, NHID, NH2, 0);
  // sequential normalize-scan
  scan_k<<<32, 1024, 0, stream>>>(Mmat, Vbuf, b0, BN, bfinal);
  // outputs = BN @ dec_w.T + dec_b
  gemm128_k<3><<<dim3(8, 16), 256, 0, stream>>>(BN, B4, outp, dec_b, NHID, NTOK, NTOK);
}